// Round 2
// baseline (395.896 us; speedup 1.0000x reference)
//
#include <hip/hip_runtime.h>
#include <math.h>

namespace {
constexpr int D     = 192;
constexpr int HW    = 256 * 512;        // 131072
constexpr int TOTAL = 2 * HW;           // 262144 pixels
constexpr unsigned ROWB = (unsigned)HW * 4u;   // bytes per depth slice (512 KB)

// Correctly-rounded s/5 in 3 ops (Markstein): bit-exact vs IEEE s/5.0f for
// all normal s >= 0 (our s in [0,5)).
__device__ __forceinline__ float div5(float s) {
    const float c = 0.2f;
    float q = s * c;
    float r = __builtin_fmaf(-5.0f, q, s);
    return __builtin_fmaf(r, c, q);
}

// Uniform SGPR base + 32-bit byte offset -> global_load v, voff, s[base]
__device__ __forceinline__ float ldx(const float* __restrict__ xn, unsigned bo) {
    return *reinterpret_cast<const float*>(
               reinterpret_cast<const char*>(xn) + bo);
}

__device__ __forceinline__ bool in_range(int d, int lo, unsigned wd) {
    return (unsigned)(d - lo) <= wd;
}

// Streaming modal-mask state machine over ONE 96-depth segment.
// Lower role (d 0..95): identical fold to the reference (bprev seeded 1.0).
// Upper role (d 96..191): bprev seeded with b[95]; sentinel last_fall/index_l
// = -1 means "no fall in this segment yet"; fra = first strict-rise position
// anywhere in the segment (D = none) for the cross-segment index_r case.
struct Mach {
    float bprev, maxv;
    int   index, last_fall, index_l, index_r, fra;
    bool  r_found;

    __device__ __forceinline__ void initA() {
        bprev = 1.0f; maxv = -INFINITY;
        index = 0; last_fall = 0; index_l = 0; index_r = D - 1;
        fra = D; r_found = false;
    }
    __device__ __forceinline__ void initB(float seed) {
        bprev = seed; maxv = -INFINITY;
        index = 96; last_fall = -1; index_l = -1; index_r = D - 1;
        fra = D; r_found = false;
    }
    template<bool UP>
    __device__ __forceinline__ void step(int d, float b) {
        float diff = b - bprev;
        bool fall  = diff < 0.0f;
        last_fall  = fall ? d : last_fall;               // strict fall
        bool am    = b > maxv;                           // first-occurrence argmax
        maxv       = am ? b : maxv;
        index      = am ? d : index;
        index_l    = am ? last_fall : index_l;
        bool rise  = (diff > 0.0f) & (!r_found) & (!am); // first rise AFTER argmax
        index_r    = am ? (D - 1) : (rise ? (d - 1) : index_r);
        r_found    = am ? false : (r_found | rise);
        if (UP) fra = min(fra, (diff > 0.0f) ? d : D);   // first rise anywhere
        bprev = b;
    }
};

// Load chunk c (8 consecutive depths) from per-thread byte base vo4.
// NG < 8 zero-fills the tail (depth >= D guard, upper role last chunk only).
template<int NG>
__device__ __forceinline__ void ld8(const float* __restrict__ xn, unsigned vo4,
                                    int c, float (&buf)[8]) {
    #pragma unroll
    for (int j = 0; j < 8; ++j)
        buf[j] = (j < NG) ? ldx(xn, vo4 + (unsigned)(8 * c + j) * ROWB) : 0.0f;
}

// 12 chunks (96 depths), 3-buffer rotating pipeline, constant 2-chunk
// load->use distance (~700 cyc of VALU in flight vs ~900 cyc HBM latency;
// with 8 waves/SIMD of TLP on top this fully covers).
template<int LASTN, typename F>
__device__ __forceinline__ void stream12(const float* __restrict__ xn,
                                         unsigned vo4, int d0, F&& f) {
    float A[8], B[8], C[8];
    ld8<8>(xn, vo4, 0, A);
    ld8<8>(xn, vo4, 1, B);
    ld8<8>(xn, vo4, 2, C);
    int d = d0;
    auto comp = [&](float (&buf)[8]) {
        #pragma unroll
        for (int j = 0; j < 8; ++j) { f(d, buf[j]); ++d; }
    };
    comp(A); ld8<8>(xn, vo4, 3, A);
    comp(B); ld8<8>(xn, vo4, 4, B);
    comp(C); ld8<8>(xn, vo4, 5, C);
    comp(A); ld8<8>(xn, vo4, 6, A);
    comp(B); ld8<8>(xn, vo4, 7, B);
    comp(C); ld8<8>(xn, vo4, 8, C);
    comp(A); ld8<8>(xn, vo4, 9, A);
    comp(B); ld8<8>(xn, vo4, 10, B);
    comp(C); ld8<LASTN>(xn, vo4, 11, C);
    comp(A); comp(B); comp(C);
}

// One blurred pass over this thread's 96-depth segment.
// SECOND: zero b inside mask1 and accumulate the y-sums.
template<bool UP, bool SECOND>
__device__ __forceinline__ void blur_pass(const float* __restrict__ xn,
        unsigned hw4, const float (&pro)[5], int lo1, unsigned wd1,
        Mach& m, float& sum_y, float& wsum_y)
{
    constexpr int BASE  = UP ? 98 : 2;   // stream supplies x[d+2]
    constexpr int D0    = UP ? 96 : 0;
    constexpr int LASTN = UP ? 6 : 8;    // upper last chunk hits depths 192,193
    float w0, w1, w2, w3;
    if (UP) { w0 = pro[1]; w1 = pro[2]; w2 = pro[3]; w3 = pro[4]; } // x[94..97]
    else    { w0 = 0.0f;   w1 = 0.0f;   w2 = pro[0]; w3 = pro[1]; } // pad,pad,x0,x1
    if (UP) {
        // b[95] recomputed locally, bit-identical add order to the lower half.
        float s = pro[0] + pro[1]; s += pro[2]; s += pro[3]; s += pro[4];
        float b95 = div5(s);
        if (SECOND) b95 = in_range(95, lo1, wd1) ? 0.0f : b95;
        m.initB(b95);
    } else {
        m.initA();
    }
    unsigned vo4 = hw4 + (unsigned)BASE * ROWB;
    stream12<LASTN>(xn, vo4, D0, [&](int d, float xv) {
        // exact left-to-right window sum, matching reference add order
        float s = w0 + w1; s += w2; s += w3; s += xv;
        float b = div5(s);
        if (SECOND) {
            bool in1 = in_range(d, lo1, wd1);
            float xm = in1 ? w2 : 0.0f;          // y = x*mask1; x[d] == w2
            sum_y += xm;
            wsum_y = __builtin_fmaf(xm, (float)d, wsum_y);
            b = in1 ? 0.0f : b;                  // x_blur2 = x_blur * ~mask1
        }
        m.template step<UP>(d, b);
        w0 = w1; w1 = w2; w2 = w3; w3 = xv;
    });
}

// z-sums over this thread's segment (z = x * mask2nd * ~mask1).
template<bool UP>
__device__ __forceinline__ void z_pass(const float* __restrict__ xn,
        unsigned hw4, int lo1, unsigned wd1, int lo2, unsigned wd2,
        float& sz, float& wz)
{
    constexpr int BASE = UP ? 96 : 0;
    unsigned vo4 = hw4 + (unsigned)BASE * ROWB;
    stream12<8>(xn, vo4, BASE, [&](int d, float xv) {
        bool z = in_range(d, lo2, wd2) & !in_range(d, lo1, wd1);
        float xm = z ? xv : 0.0f;
        sz += xm;
        wz = __builtin_fmaf(xm, (float)d, wz);
    });
}

// Combine lower-half final state with upper-half segment summary -> exact
// global (index, index_l, index_r), then the reference finish().
__device__ __forceinline__ void merge_finish(
        float Amax, int Aidx, int Ail, int Alf, int Air, int Arf,
        float Bmax, int Bidx, int Bil, int Bir, int Bfra,
        int& lo, unsigned& wd)
{
    bool bw = Bmax > Amax;                       // strict: ties keep first occurrence
    int index   = bw ? Bidx : Aidx;
    int index_l = bw ? (Bil >= 0 ? Bil : Alf)    // no fall in B before its argmax
                     : Ail;                      //   -> A's final last_fall
    int index_r = bw ? Bir
                     : (Arf ? Air
                            : ((Bfra < D) ? (Bfra - 1) : (D - 1)));
    int r  = min(index_r - index, index - index_l);
    int t  = 2 * index - index_r - index_l;
    bool valid = (t > -3) && (t < 3);
    lo = valid ? index_l : (index - r);
    int hi = valid ? index_r : (index + r);
    wd = (unsigned)(hi - lo);
}
} // namespace

extern "C" __global__ void __launch_bounds__(256, 8)
dme_kernel(const float* __restrict__ x, float* __restrict__ out)
{
    // Pass-1 / pass-2 exchange buffers (indexed [pass][pixel]) + final sums.
    __shared__ float sAmax[2][128], sBmax[2][128];
    __shared__ int   sAidx[2][128], sAil[2][128], sAlf[2][128],
                     sAir[2][128],  sArf[2][128];
    __shared__ int   sBidx[2][128], sBil[2][128], sBir[2][128], sBfra[2][128];
    __shared__ float sSum[4][128];

    const int  tid = threadIdx.x;
    const bool UPT = tid >= 128;        // wave-uniform role split (waves 0,1 vs 2,3)
    const int  pix = tid & 127;
    const int  n   = blockIdx.x >> 10;  // 1024 blocks per image
    const int  hw  = ((blockIdx.x & 1023) << 7) | pix;
    const float* __restrict__ xn = x + (size_t)n * ((size_t)D * HW);
    const unsigned hw4 = (unsigned)hw * 4u;

    // Prologue: 5 loads for both roles (lower only needs x0,x1; the extra
    // three are in-bounds and keep the path shared). Kept in regs across
    // passes 1 and 2.
    float pro[5];
    {
        const int pb = UPT ? 93 : 0;
        unsigned bo = hw4 + (unsigned)pb * ROWB;
        #pragma unroll
        for (int k = 0; k < 5; ++k) pro[k] = ldx(xn, bo + (unsigned)k * ROWB);
    }

    // ================= pass 1: modal mask of blur(x) =================
    Mach m1; float dum0 = 0.f, dum1 = 0.f;
    if (UPT) blur_pass<true , false>(xn, hw4, pro, 0, 0u, m1, dum0, dum1);
    else     blur_pass<false, false>(xn, hw4, pro, 0, 0u, m1, dum0, dum1);

    if (!UPT) {
        sAmax[0][pix] = m1.maxv;    sAidx[0][pix] = m1.index;
        sAil [0][pix] = m1.index_l; sAlf [0][pix] = m1.last_fall;
        sAir [0][pix] = m1.index_r; sArf [0][pix] = m1.r_found ? 1 : 0;
    } else {
        sBmax[0][pix] = m1.maxv;    sBidx[0][pix] = m1.index;
        sBil [0][pix] = m1.index_l; sBir [0][pix] = m1.index_r;
        sBfra[0][pix] = m1.fra;
    }
    __syncthreads();
    int lo1; unsigned wd1;
    merge_finish(sAmax[0][pix], sAidx[0][pix], sAil[0][pix], sAlf[0][pix],
                 sAir[0][pix], sArf[0][pix],
                 sBmax[0][pix], sBidx[0][pix], sBil[0][pix], sBir[0][pix],
                 sBfra[0][pix], lo1, wd1);

    // ====== pass 2: modal mask of blur(x)*~mask1, plus y-sums ======
    Mach m2; float sy = 0.f, wy = 0.f;
    if (UPT) blur_pass<true , true>(xn, hw4, pro, lo1, wd1, m2, sy, wy);
    else     blur_pass<false, true>(xn, hw4, pro, lo1, wd1, m2, sy, wy);

    if (!UPT) {
        sAmax[1][pix] = m2.maxv;    sAidx[1][pix] = m2.index;
        sAil [1][pix] = m2.index_l; sAlf [1][pix] = m2.last_fall;
        sAir [1][pix] = m2.index_r; sArf [1][pix] = m2.r_found ? 1 : 0;
    } else {
        sBmax[1][pix] = m2.maxv;    sBidx[1][pix] = m2.index;
        sBil [1][pix] = m2.index_l; sBir [1][pix] = m2.index_r;
        sBfra[1][pix] = m2.fra;
    }
    __syncthreads();
    int lo2; unsigned wd2;
    merge_finish(sAmax[1][pix], sAidx[1][pix], sAil[1][pix], sAlf[1][pix],
                 sAir[1][pix], sArf[1][pix],
                 sBmax[1][pix], sBidx[1][pix], sBil[1][pix], sBir[1][pix],
                 sBfra[1][pix], lo2, wd2);

    // ========= pass 3: z-sums (z = x * ~mask1 * mask2nd) =========
    float sz = 0.f, wz = 0.f;
    if (UPT) z_pass<true >(xn, hw4, lo1, wd1, lo2, wd2, sz, wz);
    else     z_pass<false>(xn, hw4, lo1, wd1, lo2, wd2, sz, wz);

    if (!UPT) {
        sSum[0][pix] = sy; sSum[1][pix] = wy;
        sSum[2][pix] = sz; sSum[3][pix] = wz;
    }
    __syncthreads();
    if (UPT) {
        float SY = sSum[0][pix] + sy, WY = sSum[1][pix] + wy;
        float SZ = sSum[2][pix] + sz, WZ = sSum[3][pix] + wz;
        bool  v = SY >= SZ;
        float S = v ? SY : SZ;
        float W = v ? WY : WZ;
        out[(size_t)n * HW + hw] = W / S;   // == sum(xm*d)/sum(xm)
    }
}

extern "C" void kernel_launch(void* const* d_in, const int* in_sizes, int n_in,
                              void* d_out, int out_size, void* d_ws, size_t ws_size,
                              hipStream_t stream)
{
    const float* x   = (const float*)d_in[0];
    float*       out = (float*)d_out;
    dim3 block(256), grid(TOTAL / 128);   // 2048 blocks = 8 blocks/CU = 32 waves/CU
    hipLaunchKernelGGL(dme_kernel, grid, block, 0, stream, x, out);
}